// Round 15
// baseline (1290.497 us; speedup 1.0000x reference)
//
#include <hip/hip_runtime.h>
#include <hip/hip_bf16.h>

typedef __attribute__((ext_vector_type(8))) short short8;
typedef __attribute__((ext_vector_type(4))) float f32x4;

__device__ __forceinline__ unsigned short f2bf(float v) {
    __hip_bfloat16 h = __float2bfloat16(v);   // RNE
    return *reinterpret_cast<unsigned short*>(&h);
}
__device__ __forceinline__ float bf2f(unsigned short u) {
    union { unsigned int i; float f; } x;
    x.i = (unsigned int)u << 16;
    return x.f;
}

constexpr int MAXB = 2048;   // max fine buckets (N/64 = 1563 here)
constexpr int CAP  = 2048;   // slots per bucket; mean load 1024, sd 32 -> safe

// ---------------------------------------------------------------------------
// Weight pre-transpose: Wt[(r*H + h)*64 + d], r=R slot = Wself. This is the
// K=576 concatenated operand for the fused layer kernel.
// ---------------------------------------------------------------------------
template<int H>
__global__ __launch_bounds__(256) void transpose_w(
    const float* __restrict__ W, const float* __restrict__ Wself,
    unsigned short* __restrict__ Wt, int R)
{
    int i = blockIdx.x * 256 + threadIdx.x;
    int total = (R + 1) * H * 64;
    if (i >= total) return;
    int d = i & 63;
    int hh = i >> 6;               // r*H + h
    int r = hh / H, h = hh % H;
    float v = (r < R) ? W[((size_t)r * 64 + d) * H + h]
                      : Wself[(size_t)d * H + h];
    Wt[i] = f2bf(v);
}

// ---------------------------------------------------------------------------
// feat fp32 -> bf16 table (one-time, 12.8 MB).
// ---------------------------------------------------------------------------
__global__ __launch_bounds__(256) void f32_to_bf16(
    const float* __restrict__ in, unsigned short* __restrict__ out, int total4)
{
    int i = blockIdx.x * 256 + threadIdx.x;
    if (i >= total4) return;
    float4 v = *(const float4*)&in[(size_t)i * 4];
    ushort4 u;
    u.x = f2bf(v.x); u.y = f2bf(v.y); u.z = f2bf(v.z); u.w = f2bf(v.w);
    *(ushort4*)&out[(size_t)i * 4] = u;
}

// ---------------------------------------------------------------------------
// Bucket partition (single pass, fixed-capacity windows).
// Record: (src << 9) | ((dst & 63) << 3) | et.
// ---------------------------------------------------------------------------
__global__ __launch_bounds__(256) void zero_int(int* __restrict__ p, int n) {
    int i = blockIdx.x * 256 + threadIdx.x;
    if (i < n) p[i] = 0;
}

__global__ __launch_bounds__(256) void partition_fine(
    const int* __restrict__ src, const int* __restrict__ dst,
    const int* __restrict__ et, int* __restrict__ cnt,
    int* __restrict__ rec, int E, int N, int B, int CH)
{
    __shared__ int hist[MAXB];
    __shared__ int base[MAXB];
    __shared__ int cntl[MAXB];
    const int t = threadIdx.x;
    const int e0 = blockIdx.x * CH, e1 = min(E, e0 + CH);

    for (int i = t; i < B; i += 256) hist[i] = 0;
    __syncthreads();
    for (int e = e0 + t; e < e1; e += 256) atomicAdd(&hist[dst[e] >> 6], 1);
    __syncthreads();
    for (int i = t; i < B; i += 256) {
        int h = hist[i];
        base[i] = h ? atomicAdd(&cnt[i], h) : 0;
        cntl[i] = 0;
    }
    __syncthreads();
    for (int e = e0 + t; e < e1; e += 256) {
        int d = dst[e];
        int b = d >> 6;
        int pos = base[b] + atomicAdd(&cntl[b], 1);
        if (pos < CAP)
            rec[(size_t)b * CAP + pos] = (src[e] << 9) | ((d & 63) << 3) | et[e];
    }
}

// ---------------------------------------------------------------------------
// Per-bucket 512-bin counting sort by cell key (dst&63)*8+et. Payload keeps
// the FULL record (src<<9|cell) so the gather knows each edge's target cell.
// cell_beg[b*513 + k]: absolute offsets; entry 512 = bucket end.
// ---------------------------------------------------------------------------
__global__ __launch_bounds__(256) void bucket_sort512(
    const int* __restrict__ cnt, const int* __restrict__ rec,
    int* __restrict__ srec, int* __restrict__ cell_beg)
{
    __shared__ int hist[512];
    __shared__ int ts[256];
    __shared__ int cur[512];
    const int b = blockIdx.x;
    const int t = threadIdx.x;
    const int p0 = b * CAP;
    const int p1 = p0 + cnt[b];

    hist[t] = 0; hist[t + 256] = 0;
    __syncthreads();
    for (int p = p0 + t; p < p1; p += 256)
        atomicAdd(&hist[rec[p] & 511], 1);
    __syncthreads();
    int a0 = hist[2 * t], a1 = hist[2 * t + 1];
    int s = a0 + a1;
    ts[t] = s;
    __syncthreads();
    for (int off = 1; off < 256; off <<= 1) {
        int x = (t >= off) ? ts[t - off] : 0;
        __syncthreads();
        ts[t] += x;
        __syncthreads();
    }
    int run = ts[t] - s;
    cur[2 * t]     = p0 + run;
    cur[2 * t + 1] = p0 + run + a0;
    cell_beg[(size_t)b * 513 + 2 * t]     = p0 + run;
    cell_beg[(size_t)b * 513 + 2 * t + 1] = p0 + run + a0;
    if (t == 0) cell_beg[(size_t)b * 513 + 512] = p1;
    __syncthreads();
    for (int p = p0 + t; p < p1; p += 256) {
        int rv = rec[p];
        int pos = atomicAdd(&cur[rv & 511], 1);
        srec[pos] = rv;
    }
}

// ---------------------------------------------------------------------------
// Fused RGCN layer, edge-parallel gather. Block = 16 dst nodes (grid 4*B).
// Phase 1: zero Sf[144][68] fp32; write self rows to et=8 cells (plain
//   stores); 8 half-waves stride the block's contiguous sorted edge range,
//   each edge = broadcast record + 128-B row gather + 2 ds_add_f32/lane.
// Phase 2: wave mt computes out[node][mt*16..+16] = S[node][0:576].Wt via 18
//   chained MFMAs; fragments built from Sf with in-register f32->bf16.
//   Operand-swapped layout (R10-verified): D row=quad*4+i -> h, col=m -> node.
// ---------------------------------------------------------------------------
template<int H, bool RELUOUT, bool F32OUT>
__global__ __launch_bounds__(256) void rgcn_layer(
    const unsigned int* __restrict__ tbl32,   // [N][32] packed bf16 (64 cols)
    const unsigned short* __restrict__ Wt,    // [9*H][64] bf16
    const float* __restrict__ bias,           // [H]
    const int* __restrict__ cell_beg,         // [B][513]
    const int* __restrict__ srec,             // sorted records, bucket-strided
    void* __restrict__ outv, int N)
{
    constexpr int CS = 68;                    // floats per cell (64 + 4 pad)
    __shared__ float Sf[144 * CS];            // 39,168 B -> 4 blocks/CU
    const int tid = threadIdx.x;
    const int b = blockIdx.x >> 2;
    const int sb = blockIdx.x & 3;
    const int base = b * 64 + sb * 16;        // first dst node
    const int* cb = cell_beg + (size_t)b * 513 + sb * 128;

    // ---- zero Sf ----
    float4* Sf4 = (float4*)Sf;
    #pragma unroll
    for (int i = tid; i < 144 * CS / 4; i += 256)
        Sf4[i] = make_float4(0.f, 0.f, 0.f, 0.f);
    __syncthreads();

    // ---- self rows (r=8 cells; atomics never target et==8) ----
    #pragma unroll
    for (int k = 0; k < 2; ++k) {
        int j = tid + k * 256;                // 512 slots = 16 rows x 32 uints
        int row = j >> 5, cc = j & 31;
        int nd = base + row;
        if (nd < N) {
            unsigned int v = tbl32[(size_t)nd * 32 + cc];
            float* tgt = &Sf[(row * 9 + 8) * CS + 2 * cc];
            tgt[0] = bf2f((unsigned short)(v & 0xffff));
            tgt[1] = bf2f((unsigned short)(v >> 16));
        }
    }

    // ---- edge-parallel gather (half-wave per edge, 2-deep unroll) ----
    const int hw = tid >> 5, c = tid & 31;
    const int beg = cb[0], end = cb[128];
    int p = beg + hw;
    for (; p + 8 < end; p += 16) {
        int rv0 = srec[p], rv1 = srec[p + 8];
        unsigned int v0 = tbl32[(size_t)(rv0 >> 9) * 32 + c];
        unsigned int v1 = tbl32[(size_t)(rv1 >> 9) * 32 + c];
        int ci0 = ((rv0 >> 3) & 15) * 9 + (rv0 & 7);
        int ci1 = ((rv1 >> 3) & 15) * 9 + (rv1 & 7);
        atomicAdd(&Sf[ci0 * CS + 2 * c],     bf2f((unsigned short)(v0 & 0xffff)));
        atomicAdd(&Sf[ci0 * CS + 2 * c + 1], bf2f((unsigned short)(v0 >> 16)));
        atomicAdd(&Sf[ci1 * CS + 2 * c],     bf2f((unsigned short)(v1 & 0xffff)));
        atomicAdd(&Sf[ci1 * CS + 2 * c + 1], bf2f((unsigned short)(v1 >> 16)));
    }
    for (; p < end; p += 8) {
        int rv = srec[p];
        unsigned int v = tbl32[(size_t)(rv >> 9) * 32 + c];
        int ci = ((rv >> 3) & 15) * 9 + (rv & 7);
        atomicAdd(&Sf[ci * CS + 2 * c],     bf2f((unsigned short)(v & 0xffff)));
        atomicAdd(&Sf[ci * CS + 2 * c + 1], bf2f((unsigned short)(v >> 16)));
    }
    __syncthreads();

    // ---- MFMA over K=576 ----
    const int w = tid >> 6, lane = tid & 63;
    const int m = lane & 15, quad = lane >> 4;
    constexpr int MT = H / 16;                // 4 (H=64) or 2 (H=32)
    if (w < MT) {
        const int mt = w;
        const int nd = base + m;
        f32x4 acc = (f32x4){0.f, 0.f, 0.f, 0.f};
        #pragma unroll
        for (int ch = 0; ch < 18; ++ch) {
            int r = ch >> 1, kh = ch & 1;
            const float* sp = &Sf[(m * 9 + r) * CS + kh * 32 + quad * 8];
            float4 f0 = *(const float4*)&sp[0];
            float4 f1 = *(const float4*)&sp[4];
            union { unsigned short us[8]; short8 s8; } u;
            u.us[0] = f2bf(f0.x); u.us[1] = f2bf(f0.y);
            u.us[2] = f2bf(f0.z); u.us[3] = f2bf(f0.w);
            u.us[4] = f2bf(f1.x); u.us[5] = f2bf(f1.y);
            u.us[6] = f2bf(f1.z); u.us[7] = f2bf(f1.w);
            short8 wf = *(const short8*)
                &Wt[((size_t)(r * H + mt * 16 + m)) * 64 + kh * 32 + quad * 8];
            acc = __builtin_amdgcn_mfma_f32_16x16x32_bf16(wf, u.s8, acc, 0, 0, 0);
        }
        if (nd < N) {
            float4 bv = *(const float4*)&bias[mt * 16 + quad * 4];
            float o0 = acc[0] + bv.x, o1 = acc[1] + bv.y;
            float o2 = acc[2] + bv.z, o3 = acc[3] + bv.w;
            if (RELUOUT) {
                o0 = fmaxf(o0, 0.f); o1 = fmaxf(o1, 0.f);
                o2 = fmaxf(o2, 0.f); o3 = fmaxf(o3, 0.f);
            }
            if constexpr (F32OUT) {
                float* out = (float*)outv;
                *(float4*)&out[(size_t)nd * H + mt * 16 + quad * 4] =
                    make_float4(o0, o1, o2, o3);
            } else {
                unsigned short* out = (unsigned short*)outv;
                ushort4 uo;
                uo.x = f2bf(o0); uo.y = f2bf(o1); uo.z = f2bf(o2); uo.w = f2bf(o3);
                *(ushort4*)&out[(size_t)nd * H + mt * 16 + quad * 4] = uo;
            }
        }
    }
}

extern "C" void kernel_launch(void* const* d_in, const int* in_sizes, int n_in,
                              void* d_out, int out_size, void* d_ws, size_t ws_size,
                              hipStream_t stream)
{
    const float* feat = (const float*)d_in[0];
    const int*   src  = (const int*)d_in[1];
    const int*   dst  = (const int*)d_in[2];
    const int*   et   = (const int*)d_in[3];
    const float* W1   = (const float*)d_in[4];
    const float* Ws1  = (const float*)d_in[5];
    const float* b1   = (const float*)d_in[6];
    const float* W2   = (const float*)d_in[7];
    const float* Ws2  = (const float*)d_in[8];
    const float* b2   = (const float*)d_in[9];
    float* out = (float*)d_out;

    const int N = in_sizes[0] / 64;           // 100000
    const int E = in_sizes[1];                // 1600000
    const int R = in_sizes[4] / (64 * 64);    // 8
    const int B = (N + 63) / 64;              // 1563 fine buckets

    // Workspace layout
    unsigned short* featb = (unsigned short*)d_ws;            // [N][64] bf16
    unsigned short* h1    = featb + (size_t)N * 64;           // [N][64] bf16
    unsigned short* Wt1   = h1 + (size_t)N * 64;              // [(R+1)*64*64]
    unsigned short* Wt2   = Wt1 + (size_t)(R + 1) * 64 * 64;  // [(R+1)*32*64]
    int* cnt      = (int*)(Wt2 + (size_t)(R + 1) * 32 * 64);  // [B]
    int* cell_beg = cnt + B;                                  // [B*513]
    int* rec      = cell_beg + (size_t)B * 513;               // [B*CAP]
    int* srec     = rec + (size_t)B * CAP;                    // [B*CAP]

    const dim3 blk(256);
    const int P  = 128;                       // partition blocks
    const int CH = (E + P - 1) / P;           // 12500 edges per block

    // ---- Prep: weights (bf16, [r][h][d], self appended) + feat bf16 ----
    transpose_w<64><<<((R + 1) * 64 * 64 + 255) / 256, blk, 0, stream>>>(W1, Ws1, Wt1, R);
    transpose_w<32><<<((R + 1) * 32 * 64 + 255) / 256, blk, 0, stream>>>(W2, Ws2, Wt2, R);
    f32_to_bf16<<<(N * 16 + 255) / 256, blk, 0, stream>>>(feat, featb, N * 16);

    // ---- Edge index: bucket partition + 512-cell counting sort ----
    zero_int<<<(B + 255) / 256, blk, 0, stream>>>(cnt, B);
    partition_fine<<<P, blk, 0, stream>>>(src, dst, et, cnt, rec, E, N, B, CH);
    bucket_sort512<<<B, blk, 0, stream>>>(cnt, rec, srec, cell_beg);

    // ---- Layer 1: h1 = relu(gather-sum(feat).Wcat1 + b1), bf16 ----
    rgcn_layer<64, true, false><<<4 * B, blk, 0, stream>>>(
        (const unsigned int*)featb, Wt1, b1, cell_beg, srec, h1, N);

    // ---- Layer 2: out = gather-sum(h1).Wcat2 + b2, fp32 ----
    rgcn_layer<32, false, true><<<4 * B, blk, 0, stream>>>(
        (const unsigned int*)h1, Wt2, b2, cell_beg, srec, out, N);
}